// Round 9
// baseline (140.763 us; speedup 1.0000x reference)
//
#include <hip/hip_runtime.h>
#include <math.h>

#define SA_N   8192
#define SA_IN  512
#define SA_D   64
#define G_SPL  16
#define LOG2E  1.44269504f

typedef short s16x8 __attribute__((ext_vector_type(8)));
typedef float f32x16 __attribute__((ext_vector_type(16)));

#define MFMA32(A, B, C) __builtin_amdgcn_mfma_f32_32x32x16_bf16((A), (B), (C), 0, 0, 0)

static __device__ __forceinline__ unsigned short f2bf_rn(float x) {
    unsigned int u = __float_as_uint(x);
    unsigned int r = (u + 0x7FFFu + ((u >> 16) & 1u)) >> 16;
    return (unsigned short)r;
}

static __device__ __forceinline__ void trunc_split(float f, unsigned short* hi, unsigned short* lo) {
    unsigned int u = __float_as_uint(f);
    *hi = (unsigned short)(u >> 16);
    float lf = f - __uint_as_float(u & 0xFFFF0000u);
    *lo = (unsigned short)(__float_as_uint(lf) >> 16);
}

// pack hi16 of two fp32 (trunc) into one dword — single v_perm_b32
static __device__ __forceinline__ unsigned int pack_hi16(unsigned int u0, unsigned int u1) {
    return __builtin_amdgcn_perm(u1, u0, 0x07060302u);
}

// ---- Kernel P: one-shot preprocessing ----
// blocks 0..1023:   x (16 MB f32) -> Xhi/Xlo bf16 (trunc split, bit-identical
//                   to the old per-block split8) — x was being re-split 3x in qkv.
// blocks 1024..1119: W -> hi/lo (Q,K) / rn (V), same as R7's prep_w (validated).
__global__ __launch_bounds__(256) void prep_kernel(
    const float* __restrict__ in,
    const float* __restrict__ Wq, const float* __restrict__ Wk, const float* __restrict__ Wv,
    unsigned short* __restrict__ Xhi, unsigned short* __restrict__ Xlo,
    unsigned short* __restrict__ WqH, unsigned short* __restrict__ WqL,
    unsigned short* __restrict__ WkH, unsigned short* __restrict__ WkL,
    unsigned short* __restrict__ WvR)
{
    const int b = blockIdx.x;
    if (b < 1024) {
        const int base = (b * 256 + threadIdx.x) * 4;       // float4 index, 4 per thread
        const float4* src = (const float4*)in;
#pragma unroll
        for (int j = 0; j < 4; ++j) {
            const float4 v = src[base + j];
            ushort4 H, L;
            trunc_split(v.x, &H.x, &L.x);
            trunc_split(v.y, &H.y, &L.y);
            trunc_split(v.z, &H.z, &L.z);
            trunc_split(v.w, &H.w, &L.w);
            ((ushort4*)Xhi)[base + j] = H;
            ((ushort4*)Xlo)[base + j] = L;
        }
    } else {
        const int i   = (b - 1024) * 256 + threadIdx.x;     // 24576 float4s
        const int mat = i >> 13;
        const int j   = i & 8191;
        const float4 v = (mat == 0 ? (const float4*)Wq
                        : mat == 1 ? (const float4*)Wk
                                   : (const float4*)Wv)[j];
        const float f[4] = {v.x, v.y, v.z, v.w};
        if (mat < 2) {
            unsigned short hs[4], ls[4];
#pragma unroll
            for (int e = 0; e < 4; ++e) trunc_split(f[e], &hs[e], &ls[e]);
            ushort4 H = {hs[0], hs[1], hs[2], hs[3]};
            ushort4 L = {ls[0], ls[1], ls[2], ls[3]};
            unsigned short* WH = mat ? WkH : WqH;
            unsigned short* WL = mat ? WkL : WqL;
            *(ushort4*)(WH + (size_t)j * 4) = H;
            *(ushort4*)(WL + (size_t)j * 4) = L;
        } else {
            ushort4 R = {f2bf_rn(f[0]), f2bf_rn(f[1]), f2bf_rn(f[2]), f2bf_rn(f[3])};
            *(ushort4*)(WvR + (size_t)j * 4) = R;
        }
    }
}

// ---- Kernel A: QKV, restructured — one wave = one full-K 32x32 tile ----
// R8 post-mortem: layout/math verified correct; the failure was a store-
// coverage bug — the K/V epilogue kept the old 32-row store (st4[0..256))
// and never wrote the wr=1 sub-tile (st4[256..512)) -> half of K/V stale.
// Fixed: 2 uint4/thread covering both sub-tiles; rows0*64 + 2048 is exactly
// tile jt=rt*2+1's offset, so attn's expected layout is preserved verbatim.
__global__ __launch_bounds__(256, 2) void qkv_kernel(
    const unsigned short* __restrict__ Xhi, const unsigned short* __restrict__ Xlo,
    const unsigned short* __restrict__ WqH, const unsigned short* __restrict__ WqL,
    const unsigned short* __restrict__ WkH, const unsigned short* __restrict__ WkL,
    const unsigned short* __restrict__ WvR,
    const float* __restrict__ bq, const float* __restrict__ bk, const float* __restrict__ bv,
    unsigned short* __restrict__ Qhi, unsigned short* __restrict__ Qlo,
    unsigned short* __restrict__ KhiF, unsigned short* __restrict__ VF)
{
    __shared__ __align__(16) unsigned short stage[8192];     // 16 KB
    const int t    = threadIdx.x;
    const int w    = t >> 6;
    const int lane = t & 63;
    const int h    = lane >> 5;
    const int q32  = lane & 31;
    const int wr   = w >> 1;            // row half (0..1)
    const int wc   = w & 1;             // col half (0..1)
    const int mat  = blockIdx.x >> 7;   // 0=q,1=k,2=v (128 blocks per mat)
    const int rt   = blockIdx.x & 127;
    const int rows0 = rt * 64;

    const unsigned short* WH = (mat == 0) ? WqH : (mat == 1 ? WkH : WvR);
    const unsigned short* WL = (mat == 0) ? WqL : WkL;   // unused when mat==2
    const float* B = (mat == 0) ? bq : (mat == 1 ? bk : bv);

    const unsigned short* xh_p = Xhi + (size_t)(rows0 + wr * 32 + q32) * SA_IN + h * 8;
    const unsigned short* xl_p = Xlo + (size_t)(rows0 + wr * 32 + q32) * SA_IN + h * 8;
    const unsigned short* wh_p = WH  + (size_t)(wc * 32 + q32) * SA_IN + h * 8;
    const unsigned short* wl_p = WL  + (size_t)(wc * 32 + q32) * SA_IN + h * 8;

    f32x16 accA = {}, accB = {};
    if (mat < 2) {
#pragma unroll 4
        for (int ks = 0; ks < 32; ++ks) {
            const s16x8 xh = *(const s16x8*)(xh_p + ks * 16);
            const s16x8 xl = *(const s16x8*)(xl_p + ks * 16);
            const s16x8 ah = *(const s16x8*)(wh_p + ks * 16);
            const s16x8 al = *(const s16x8*)(wl_p + ks * 16);
            accA = MFMA32(ah, xh, accA);
            accB = MFMA32(ah, xl, accB);
            accA = MFMA32(al, xh, accA);
        }
    } else {
#pragma unroll 4
        for (int ks = 0; ks < 32; ++ks) {
            const s16x8 xh = *(const s16x8*)(xh_p + ks * 16);
            const s16x8 ah = *(const s16x8*)(wh_p + ks * 16);
            accA = MFMA32(ah, xh, accA);
        }
    }

#pragma unroll
    for (int r = 0; r < 16; ++r) {
        const int o = wc * 32 + (r & 3) + 8 * (r >> 2) + 4 * h;
        float val = accA[r] + (mat < 2 ? accB[r] : 0.f) + B[o];
        if (mat == 0) {
            val *= LOG2E;
            unsigned short hi, lo;
            trunc_split(val, &hi, &lo);
            stage[(wr * 32 + q32) * 64 + o]        = hi;
            stage[4096 + (wr * 32 + q32) * 64 + o] = lo;
        } else if (mat == 1) {
            const int kl_ = ((o >> 4) * 64 + ((o >> 3) & 1) * 32 + q32) * 8 + (o & 7);
            stage[wr * 2048 + kl_] = f2bf_rn(val);
        } else {
            const int hp = (q32 >> 2) & 1;
            const int ip = (q32 & 3) + ((q32 >> 3) & 1) * 4;
            const int vl_ = ((o >> 5) * 2 + (q32 >> 4)) * 512
                          + hp * 256 + (o & 31) * 8 + ip;
            stage[wr * 2048 + vl_] = f2bf_rn(val);
        }
    }
    __syncthreads();

    {
        const uint4* st4 = (const uint4*)stage;
        if (mat == 0) {
            // hi: st4[0..512) -> Qhi, lo: st4[512..1024) -> Qlo; contiguous 64 rows
#pragma unroll
            for (int j = 0; j < 4; ++j) {
                const int i = t + j * 256;
                unsigned short* dst = (i < 512 ? Qhi + (size_t)rows0 * 64 + i * 8
                                               : Qlo + (size_t)rows0 * 64 + (i - 512) * 8);
                *(uint4*)dst = st4[i];
            }
        } else if (mat == 1) {
#pragma unroll
            for (int j = 0; j < 2; ++j) {
                const int i = t + j * 256;      // 512 uint4 = both 32-row tiles
                *(uint4*)(KhiF + (size_t)rows0 * 64 + i * 8) = st4[i];
            }
        } else {
#pragma unroll
            for (int j = 0; j < 2; ++j) {
                const int i = t + j * 256;
                *(uint4*)(VF + (size_t)rows0 * 64 + i * 8) = st4[i];
            }
        }
    }
}

// ---- Kernel B: MFMA flash attention — R6 LDS-relay, 8-wave blocks (unchanged) ----
__global__ __launch_bounds__(512, 2) void attn_kernel(
    const unsigned short* __restrict__ Qhi, const unsigned short* __restrict__ Qlo,
    const unsigned short* __restrict__ KhiF, const unsigned short* __restrict__ VF,
    unsigned short* __restrict__ Opart, float* __restrict__ Lpart)
{
    __shared__ __align__(16) unsigned short kbuf[2][2][2048];   // 16 KB
    const int t    = threadIdx.x;
    const int w    = t >> 6;            // 0..7
    const int lane = t & 63;
    const int h    = lane >> 5;
    const int q32  = lane & 31;
    const int qb   = blockIdx.x >> 4;   // 0..31
    const int g    = blockIdx.x & 15;
    const int q0   = (qb * 8 + w) * 32;
    const int jt0  = g * 16;

    const int half = t >> 8;            // 0 = K-stager, 1 = V-stager
    const int ti   = t & 255;

    s16x8 qh[4], ql[4];
#pragma unroll
    for (int s = 0; s < 4; ++s) {
        const size_t off = (size_t)(q0 + q32) * 64 + s * 16 + h * 8;
        qh[s] = *reinterpret_cast<const s16x8*>(Qhi + off);
        ql[s] = *reinterpret_cast<const s16x8*>(Qlo + off);
    }

    const unsigned short* SRC = half ? VF : KhiF;

    // prologue: stage tile jt0 into buffer 0 (one uint4 per thread)
    {
        const uint4 a = *(const uint4*)(SRC + (size_t)jt0 * 2048 + ti * 8);
        *(uint4*)&kbuf[0][half][ti * 8] = a;
    }
    __syncthreads();

    f32x16 O0 = {}, O1 = {};
    float lsum = 0.f;

    for (int it = 0; it < 16; ++it) {
        const int p = it & 1;

        // relay-prefetch next tile into registers (4 VGPR)
        uint4 na;
        if (it < 15) {
            na = *(const uint4*)(SRC + (size_t)(jt0 + it + 1) * 2048 + ti * 8);
        }

        s16x8 kh[4], vv[4];
#pragma unroll
        for (int s = 0; s < 4; ++s) {
            kh[s] = *(const s16x8*)&kbuf[p][0][(s * 64 + lane) * 8];
            vv[s] = *(const s16x8*)&kbuf[p][1][(s * 64 + lane) * 8];
        }

        // two independent 4-deep chains
        f32x16 Sa = {}, Sb = {};
        __builtin_amdgcn_s_setprio(1);
#pragma unroll
        for (int s = 0; s < 4; ++s) {
            Sa = MFMA32(kh[s], qh[s], Sa);
            Sb = MFMA32(kh[s], ql[s], Sb);
        }
        __builtin_amdgcn_s_setprio(0);

        float e[16];
#pragma unroll
        for (int r = 0; r < 16; ++r) e[r] = __builtin_amdgcn_exp2f(Sa[r] + Sb[r]);
        lsum += (((e[0] + e[1]) + (e[2] + e[3])) + ((e[4] + e[5]) + (e[6] + e[7])))
              + (((e[8] + e[9]) + (e[10] + e[11])) + ((e[12] + e[13]) + (e[14] + e[15])));

        // P^T B-fragments = this lane's C registers in order (pi-permuted V)
        union { unsigned int u[4]; s16x8 v; } P0, P1;
#pragma unroll
        for (int j2 = 0; j2 < 4; ++j2) {
            P0.u[j2] = pack_hi16(__float_as_uint(e[2 * j2]),     __float_as_uint(e[2 * j2 + 1]));
            P1.u[j2] = pack_hi16(__float_as_uint(e[8 + 2 * j2]), __float_as_uint(e[8 + 2 * j2 + 1]));
        }

        __builtin_amdgcn_s_setprio(1);
        O0 = MFMA32(vv[0], P0.v, O0);
        O0 = MFMA32(vv[1], P1.v, O0);
        O1 = MFMA32(vv[2], P0.v, O1);
        O1 = MFMA32(vv[3], P1.v, O1);
        __builtin_amdgcn_s_setprio(0);

        if (it < 15) {
            *(uint4*)&kbuf[1 - p][half][ti * 8] = na;
        }
        __syncthreads();
    }

    lsum += __shfl_xor(lsum, 32, 64);

    const size_t qg = (size_t)g * SA_N + q0 + q32;
#pragma unroll
    for (int rg = 0; rg < 4; ++rg) {
        const int d0 = 8 * rg + 4 * h;
        uint2 s0, s1;
        s0.x = (unsigned int)f2bf_rn(O0[4 * rg + 0]) | ((unsigned int)f2bf_rn(O0[4 * rg + 1]) << 16);
        s0.y = (unsigned int)f2bf_rn(O0[4 * rg + 2]) | ((unsigned int)f2bf_rn(O0[4 * rg + 3]) << 16);
        s1.x = (unsigned int)f2bf_rn(O1[4 * rg + 0]) | ((unsigned int)f2bf_rn(O1[4 * rg + 1]) << 16);
        s1.y = (unsigned int)f2bf_rn(O1[4 * rg + 2]) | ((unsigned int)f2bf_rn(O1[4 * rg + 3]) << 16);
        *(uint2*)(Opart + qg * 64 + d0)      = s0;
        *(uint2*)(Opart + qg * 64 + d0 + 32) = s1;
    }
    if (h == 0) Lpart[qg] = lsum;
}

// ---- Kernel C: combine 16 partials, normalize ----
__global__ __launch_bounds__(256) void combine_kernel(
    const unsigned short* __restrict__ Opart, const float* __restrict__ Lpart,
    float* __restrict__ out)
{
    const int tid = blockIdx.x * 256 + threadIdx.x;
    const int q  = tid >> 5;
    const int dp = tid & 31;
    const unsigned int* OP = (const unsigned int*)Opart;
    float s0 = 0.f, s1 = 0.f, lt = 0.f;
#pragma unroll
    for (int g = 0; g < G_SPL; ++g) {
        const unsigned int v = OP[((size_t)g * SA_N + q) * 32 + dp];
        s0 += __uint_as_float(v << 16);
        s1 += __uint_as_float(v & 0xFFFF0000u);
        lt += Lpart[(size_t)g * SA_N + q];
    }
    float2 r = { s0 / lt, s1 / lt };
    *(float2*)&out[(size_t)q * 64 + dp * 2] = r;
}

extern "C" void kernel_launch(void* const* d_in, const int* in_sizes, int n_in,
                              void* d_out, int out_size, void* d_ws, size_t ws_size,
                              hipStream_t stream) {
    const float* input = (const float*)d_in[0];
    const float* Wq    = (const float*)d_in[1];
    const float* bq    = (const float*)d_in[2];
    const float* Wk    = (const float*)d_in[3];
    const float* bk    = (const float*)d_in[4];
    const float* Wv    = (const float*)d_in[5];
    const float* bv    = (const float*)d_in[6];
    float* out = (float*)d_out;

    const size_t SEG = (size_t)SA_N * 64;
    unsigned short* Qhi  = (unsigned short*)d_ws;
    unsigned short* Qlo  = Qhi  + SEG;
    unsigned short* KhiF = Qlo  + SEG;
    unsigned short* VF   = KhiF + SEG;
    unsigned short* Opart = VF  + SEG;               // G_SPL*N*64 bf16 = 16 MB
    float*          Lpart = (float*)(Opart + (size_t)G_SPL * SA_N * 64);
    unsigned short* WqH = (unsigned short*)(Lpart + (size_t)G_SPL * SA_N);
    unsigned short* WqL = WqH + 32768;
    unsigned short* WkH = WqL + 32768;
    unsigned short* WkL = WkH + 32768;
    unsigned short* WvR = WkL + 32768;
    unsigned short* Xhi = WvR + 32768;               // 8192*512 bf16 = 8 MB
    unsigned short* Xlo = Xhi + (size_t)SA_N * SA_IN;

    prep_kernel<<<1120, 256, 0, stream>>>(input, Wq, Wk, Wv, Xhi, Xlo,
                                          WqH, WqL, WkH, WkL, WvR);
    qkv_kernel<<<384, 256, 0, stream>>>(Xhi, Xlo, WqH, WqL, WkH, WkL, WvR,
                                        bq, bk, bv, Qhi, Qlo, KhiF, VF);
    attn_kernel<<<32 * G_SPL, 512, 0, stream>>>(Qhi, Qlo, KhiF, VF, Opart, Lpart);
    combine_kernel<<<1024, 256, 0, stream>>>(Opart, Lpart, out);
}

// Round 10
// 128.423 us; speedup vs baseline: 1.0961x; 1.0961x over previous
//
#include <hip/hip_runtime.h>
#include <math.h>

#define SA_N   8192
#define SA_IN  512
#define SA_D   64
#define G_SPL  16
#define LOG2E  1.44269504f

typedef short s16x8 __attribute__((ext_vector_type(8)));
typedef float f32x16 __attribute__((ext_vector_type(16)));

#define MFMA32(A, B, C) __builtin_amdgcn_mfma_f32_32x32x16_bf16((A), (B), (C), 0, 0, 0)

static __device__ __forceinline__ unsigned short f2bf_rn(float x) {
    unsigned int u = __float_as_uint(x);
    unsigned int r = (u + 0x7FFFu + ((u >> 16) & 1u)) >> 16;
    return (unsigned short)r;
}

static __device__ __forceinline__ void trunc_split(float f, unsigned short* hi, unsigned short* lo) {
    unsigned int u = __float_as_uint(f);
    *hi = (unsigned short)(u >> 16);
    float lf = f - __uint_as_float(u & 0xFFFF0000u);
    *lo = (unsigned short)(__float_as_uint(lf) >> 16);
}

// pack hi16 of two fp32 (trunc) into one dword — single v_perm_b32
static __device__ __forceinline__ unsigned int pack_hi16(unsigned int u0, unsigned int u1) {
    return __builtin_amdgcn_perm(u1, u0, 0x07060302u);
}

static __device__ __forceinline__ void split8(const float4 a, const float4 b, s16x8* xh, s16x8* xl) {
    union { unsigned int u[4]; s16x8 v; } H, L;
    const float f[8] = {a.x, a.y, a.z, a.w, b.x, b.y, b.z, b.w};
#pragma unroll
    for (int p = 0; p < 4; ++p) {
        const unsigned int u0 = __float_as_uint(f[2 * p]);
        const unsigned int u1 = __float_as_uint(f[2 * p + 1]);
        H.u[p] = pack_hi16(u0, u1);
        const float l0 = f[2 * p]     - __uint_as_float(u0 & 0xFFFF0000u);
        const float l1 = f[2 * p + 1] - __uint_as_float(u1 & 0xFFFF0000u);
        L.u[p] = pack_hi16(__float_as_uint(l0), __float_as_uint(l1));
    }
    *xh = H.v; *xl = L.v;
}

static __device__ __forceinline__ s16x8 pack_rn8(const float4 a, const float4 b) {
    union { unsigned int u[4]; s16x8 v; } P;
    const float f[8] = {a.x, a.y, a.z, a.w, b.x, b.y, b.z, b.w};
#pragma unroll
    for (int p = 0; p < 4; ++p)
        P.u[p] = (unsigned int)f2bf_rn(f[2 * p]) | ((unsigned int)f2bf_rn(f[2 * p + 1]) << 16);
    return P.v;
}

// ---- Kernel A: QKV via bf16x3 MFMA, split by matrix (grid 768 = 3 mats x 256 tiles) ----
// R9 post-mortem: full-K-per-wave restructure at grid 384 (1.5 blocks/CU)
// REGRESSED (~43 vs ~36 µs) — dependent MFMA chain at ~6 waves/CU, latency
// exposed. Suite-wide pattern: everything here is latency-bound; occupancy
// and amortization win, arithmetic trims are null. So: R6 structure reverted
// verbatim, ONE change — launch_bounds (256,2)->(256,3). LDS 48 KB fits 3
// blocks/CU (144<160 KB); (256,3) caps VGPR at 170 so 3 blocks become
// residency-legal (true live-set ~125 regs, spill risk low — opposite of
// R2's 32-reg squeeze).
__global__ __launch_bounds__(256, 3) void qkv_kernel(
    const float* __restrict__ in,
    const float* __restrict__ Wq, const float* __restrict__ bq,
    const float* __restrict__ Wk, const float* __restrict__ bk,
    const float* __restrict__ Wv, const float* __restrict__ bv,
    unsigned short* __restrict__ Qhi, unsigned short* __restrict__ Qlo,
    unsigned short* __restrict__ KhiF, unsigned short* __restrict__ VF)
{
    __shared__ float cbuf[2][4][64][20];                      // 40 KB
    __shared__ __align__(16) unsigned short stage[4096];      // 8 KB
    const int t    = threadIdx.x;
    const int w    = t >> 6;
    const int lane = t & 63;
    const int h    = lane >> 5;
    const int q32  = lane & 31;
    const int mat  = blockIdx.x >> 8;   // 0=q,1=k,2=v
    const int jt   = blockIdx.x & 255;
    const int rows0 = jt * 32;

    const float* W = (mat == 0) ? Wq : (mat == 1 ? Wk : Wv);
    const float* B = (mat == 0) ? bq : (mat == 1 ? bk : bv);

    f32x16 accA[2] = {};
    f32x16 accB[2] = {};

#pragma unroll 2
    for (int ksl = 0; ksl < 8; ++ksl) {
        const int ks = (w << 3) + ksl;
        const float* xp = in + (size_t)(rows0 + q32) * SA_IN + ks * 16 + h * 8;
        const float4 xa = *(const float4*)xp;
        const float4 xb = *(const float4*)(xp + 4);
        s16x8 xh, xl;
        split8(xa, xb, &xh, &xl);
#pragma unroll
        for (int mt = 0; mt < 2; ++mt) {
            const float* wp = W + (size_t)(mt * 32 + q32) * SA_IN + ks * 16 + h * 8;
            const float4 wa = *(const float4*)wp;
            const float4 wb = *(const float4*)(wp + 4);
            if (mat < 2) {
                s16x8 ah, al;
                split8(wa, wb, &ah, &al);
                accA[mt] = MFMA32(ah, xh, accA[mt]);
                accB[mt] = MFMA32(ah, xl, accB[mt]);
                accA[mt] = MFMA32(al, xh, accA[mt]);
            } else {
                const s16x8 ah = pack_rn8(wa, wb);
                accA[mt] = MFMA32(ah, xh, accA[mt]);
            }
        }
    }

#pragma unroll
    for (int mt = 0; mt < 2; ++mt) {
        f32x16 tot = accA[mt];
        if (mat < 2) {
#pragma unroll
            for (int r = 0; r < 16; ++r) tot[r] += accB[mt][r];
        }
#pragma unroll
        for (int rg = 0; rg < 4; ++rg) {
            float4 vv = { tot[4 * rg + 0], tot[4 * rg + 1],
                          tot[4 * rg + 2], tot[4 * rg + 3] };
            *(float4*)&cbuf[mt][w][lane][4 * rg] = vv;
        }
    }
    __syncthreads();
    if (w < 2) {
        const int mt = w;
        float c[16];
#pragma unroll
        for (int rg = 0; rg < 4; ++rg) {
            const float4 s0 = *(const float4*)&cbuf[mt][0][lane][4 * rg];
            const float4 s1 = *(const float4*)&cbuf[mt][1][lane][4 * rg];
            const float4 s2 = *(const float4*)&cbuf[mt][2][lane][4 * rg];
            const float4 s3 = *(const float4*)&cbuf[mt][3][lane][4 * rg];
            c[4 * rg + 0] = (s0.x + s1.x) + (s2.x + s3.x);
            c[4 * rg + 1] = (s0.y + s1.y) + (s2.y + s3.y);
            c[4 * rg + 2] = (s0.z + s1.z) + (s2.z + s3.z);
            c[4 * rg + 3] = (s0.w + s1.w) + (s2.w + s3.w);
        }
#pragma unroll
        for (int r = 0; r < 16; ++r) {
            const int o = mt * 32 + (r & 3) + 8 * (r >> 2) + 4 * h;
            float val = c[r] + B[o];
            if (mat == 0) {
                val *= LOG2E;
                unsigned short hi, lo;
                trunc_split(val, &hi, &lo);
                stage[q32 * 64 + o]        = hi;
                stage[2048 + q32 * 64 + o] = lo;
            } else if (mat == 1) {
                const int kl_ = ((o >> 4) * 64 + ((o >> 3) & 1) * 32 + q32) * 8 + (o & 7);
                stage[kl_] = f2bf_rn(val);
            } else {
                // pi-permuted V fragment: key q32 -> (s, h', i')
                const int hp = (q32 >> 2) & 1;
                const int ip = (q32 & 3) + ((q32 >> 3) & 1) * 4;
                const int vl_ = ((o >> 5) * 2 + (q32 >> 4)) * 512
                              + hp * 256 + (o & 31) * 8 + ip;
                stage[vl_] = f2bf_rn(val);
            }
        }
    }
    __syncthreads();

    {
        const uint4* st4 = (const uint4*)stage;
        if (mat == 0) {
            for (int i = t; i < 512; i += 256) {
                unsigned short* dst = ((i < 256) ? Qhi : Qlo) + (size_t)rows0 * 64 + (i & 255) * 8;
                *(uint4*)dst = st4[i];
            }
        } else if (mat == 1) {
            if (t < 256) *(uint4*)(KhiF + (size_t)jt * 2048 + t * 8) = st4[t];
        } else {
            *(uint4*)(VF + (size_t)jt * 2048 + t * 8) = st4[t];
        }
    }
}

// ---- Kernel B: MFMA flash attention — R6 LDS-relay, 8-wave blocks (unchanged) ----
__global__ __launch_bounds__(512, 2) void attn_kernel(
    const unsigned short* __restrict__ Qhi, const unsigned short* __restrict__ Qlo,
    const unsigned short* __restrict__ KhiF, const unsigned short* __restrict__ VF,
    unsigned short* __restrict__ Opart, float* __restrict__ Lpart)
{
    __shared__ __align__(16) unsigned short kbuf[2][2][2048];   // 16 KB
    const int t    = threadIdx.x;
    const int w    = t >> 6;            // 0..7
    const int lane = t & 63;
    const int h    = lane >> 5;
    const int q32  = lane & 31;
    const int qb   = blockIdx.x >> 4;   // 0..31
    const int g    = blockIdx.x & 15;
    const int q0   = (qb * 8 + w) * 32;
    const int jt0  = g * 16;

    const int half = t >> 8;            // 0 = K-stager, 1 = V-stager
    const int ti   = t & 255;

    s16x8 qh[4], ql[4];
#pragma unroll
    for (int s = 0; s < 4; ++s) {
        const size_t off = (size_t)(q0 + q32) * 64 + s * 16 + h * 8;
        qh[s] = *reinterpret_cast<const s16x8*>(Qhi + off);
        ql[s] = *reinterpret_cast<const s16x8*>(Qlo + off);
    }

    const unsigned short* SRC = half ? VF : KhiF;

    // prologue: stage tile jt0 into buffer 0 (one uint4 per thread)
    {
        const uint4 a = *(const uint4*)(SRC + (size_t)jt0 * 2048 + ti * 8);
        *(uint4*)&kbuf[0][half][ti * 8] = a;
    }
    __syncthreads();

    f32x16 O0 = {}, O1 = {};
    float lsum = 0.f;

    for (int it = 0; it < 16; ++it) {
        const int p = it & 1;

        // relay-prefetch next tile into registers (4 VGPR)
        uint4 na;
        if (it < 15) {
            na = *(const uint4*)(SRC + (size_t)(jt0 + it + 1) * 2048 + ti * 8);
        }

        s16x8 kh[4], vv[4];
#pragma unroll
        for (int s = 0; s < 4; ++s) {
            kh[s] = *(const s16x8*)&kbuf[p][0][(s * 64 + lane) * 8];
            vv[s] = *(const s16x8*)&kbuf[p][1][(s * 64 + lane) * 8];
        }

        // two independent 4-deep chains
        f32x16 Sa = {}, Sb = {};
        __builtin_amdgcn_s_setprio(1);
#pragma unroll
        for (int s = 0; s < 4; ++s) {
            Sa = MFMA32(kh[s], qh[s], Sa);
            Sb = MFMA32(kh[s], ql[s], Sb);
        }
        __builtin_amdgcn_s_setprio(0);

        float e[16];
#pragma unroll
        for (int r = 0; r < 16; ++r) e[r] = __builtin_amdgcn_exp2f(Sa[r] + Sb[r]);
        lsum += (((e[0] + e[1]) + (e[2] + e[3])) + ((e[4] + e[5]) + (e[6] + e[7])))
              + (((e[8] + e[9]) + (e[10] + e[11])) + ((e[12] + e[13]) + (e[14] + e[15])));

        // P^T B-fragments = this lane's C registers in order (pi-permuted V)
        union { unsigned int u[4]; s16x8 v; } P0, P1;
#pragma unroll
        for (int j2 = 0; j2 < 4; ++j2) {
            P0.u[j2] = pack_hi16(__float_as_uint(e[2 * j2]),     __float_as_uint(e[2 * j2 + 1]));
            P1.u[j2] = pack_hi16(__float_as_uint(e[8 + 2 * j2]), __float_as_uint(e[8 + 2 * j2 + 1]));
        }

        __builtin_amdgcn_s_setprio(1);
        O0 = MFMA32(vv[0], P0.v, O0);
        O0 = MFMA32(vv[1], P1.v, O0);
        O1 = MFMA32(vv[2], P0.v, O1);
        O1 = MFMA32(vv[3], P1.v, O1);
        __builtin_amdgcn_s_setprio(0);

        if (it < 15) {
            *(uint4*)&kbuf[1 - p][half][ti * 8] = na;
        }
        __syncthreads();
    }

    lsum += __shfl_xor(lsum, 32, 64);

    const size_t qg = (size_t)g * SA_N + q0 + q32;
#pragma unroll
    for (int rg = 0; rg < 4; ++rg) {
        const int d0 = 8 * rg + 4 * h;
        uint2 s0, s1;
        s0.x = (unsigned int)f2bf_rn(O0[4 * rg + 0]) | ((unsigned int)f2bf_rn(O0[4 * rg + 1]) << 16);
        s0.y = (unsigned int)f2bf_rn(O0[4 * rg + 2]) | ((unsigned int)f2bf_rn(O0[4 * rg + 3]) << 16);
        s1.x = (unsigned int)f2bf_rn(O1[4 * rg + 0]) | ((unsigned int)f2bf_rn(O1[4 * rg + 1]) << 16);
        s1.y = (unsigned int)f2bf_rn(O1[4 * rg + 2]) | ((unsigned int)f2bf_rn(O1[4 * rg + 3]) << 16);
        *(uint2*)(Opart + qg * 64 + d0)      = s0;
        *(uint2*)(Opart + qg * 64 + d0 + 32) = s1;
    }
    if (h == 0) Lpart[qg] = lsum;
}

// ---- Kernel C: combine 16 partials, normalize ----
__global__ __launch_bounds__(256) void combine_kernel(
    const unsigned short* __restrict__ Opart, const float* __restrict__ Lpart,
    float* __restrict__ out)
{
    const int tid = blockIdx.x * 256 + threadIdx.x;
    const int q  = tid >> 5;
    const int dp = tid & 31;
    const unsigned int* OP = (const unsigned int*)Opart;
    float s0 = 0.f, s1 = 0.f, lt = 0.f;
#pragma unroll
    for (int g = 0; g < G_SPL; ++g) {
        const unsigned int v = OP[((size_t)g * SA_N + q) * 32 + dp];
        s0 += __uint_as_float(v << 16);
        s1 += __uint_as_float(v & 0xFFFF0000u);
        lt += Lpart[(size_t)g * SA_N + q];
    }
    float2 r = { s0 / lt, s1 / lt };
    *(float2*)&out[(size_t)q * 64 + dp * 2] = r;
}

extern "C" void kernel_launch(void* const* d_in, const int* in_sizes, int n_in,
                              void* d_out, int out_size, void* d_ws, size_t ws_size,
                              hipStream_t stream) {
    const float* input = (const float*)d_in[0];
    const float* Wq    = (const float*)d_in[1];
    const float* bq    = (const float*)d_in[2];
    const float* Wk    = (const float*)d_in[3];
    const float* bk    = (const float*)d_in[4];
    const float* Wv    = (const float*)d_in[5];
    const float* bv    = (const float*)d_in[6];
    float* out = (float*)d_out;

    const size_t SEG = (size_t)SA_N * 64;
    unsigned short* Qhi  = (unsigned short*)d_ws;
    unsigned short* Qlo  = Qhi  + SEG;
    unsigned short* KhiF = Qlo  + SEG;
    unsigned short* VF   = KhiF + SEG;
    unsigned short* Opart = VF  + SEG;               // G_SPL*N*64 bf16 = 16 MB
    float*          Lpart = (float*)(Opart + (size_t)G_SPL * SA_N * 64);

    qkv_kernel<<<768, 256, 0, stream>>>(input, Wq, bq, Wk, bk, Wv, bv,
                                        Qhi, Qlo, KhiF, VF);
    attn_kernel<<<32 * G_SPL, 512, 0, stream>>>(Qhi, Qlo, KhiF, VF, Opart, Lpart);
    combine_kernel<<<1024, 256, 0, stream>>>(Opart, Lpart, out);
}

// Round 11
// 126.726 us; speedup vs baseline: 1.1108x; 1.0134x over previous
//
#include <hip/hip_runtime.h>
#include <math.h>

#define SA_N   8192
#define SA_IN  512
#define SA_D   64
#define G_SPL  16
#define LOG2E  1.44269504f

typedef short s16x8 __attribute__((ext_vector_type(8)));
typedef float f32x16 __attribute__((ext_vector_type(16)));

#define MFMA32(A, B, C) __builtin_amdgcn_mfma_f32_32x32x16_bf16((A), (B), (C), 0, 0, 0)

static __device__ __forceinline__ unsigned short f2bf_rn(float x) {
    unsigned int u = __float_as_uint(x);
    unsigned int r = (u + 0x7FFFu + ((u >> 16) & 1u)) >> 16;
    return (unsigned short)r;
}

static __device__ __forceinline__ void trunc_split(float f, unsigned short* hi, unsigned short* lo) {
    unsigned int u = __float_as_uint(f);
    *hi = (unsigned short)(u >> 16);
    float lf = f - __uint_as_float(u & 0xFFFF0000u);
    *lo = (unsigned short)(__float_as_uint(lf) >> 16);
}

// pack hi16 of two fp32 (trunc) into one dword — single v_perm_b32
static __device__ __forceinline__ unsigned int pack_hi16(unsigned int u0, unsigned int u1) {
    return __builtin_amdgcn_perm(u1, u0, 0x07060302u);
}

static __device__ __forceinline__ void split8(const float4 a, const float4 b, s16x8* xh, s16x8* xl) {
    union { unsigned int u[4]; s16x8 v; } H, L;
    const float f[8] = {a.x, a.y, a.z, a.w, b.x, b.y, b.z, b.w};
#pragma unroll
    for (int p = 0; p < 4; ++p) {
        const unsigned int u0 = __float_as_uint(f[2 * p]);
        const unsigned int u1 = __float_as_uint(f[2 * p + 1]);
        H.u[p] = pack_hi16(u0, u1);
        const float l0 = f[2 * p]     - __uint_as_float(u0 & 0xFFFF0000u);
        const float l1 = f[2 * p + 1] - __uint_as_float(u1 & 0xFFFF0000u);
        L.u[p] = pack_hi16(__float_as_uint(l0), __float_as_uint(l1));
    }
    *xh = H.v; *xl = L.v;
}

static __device__ __forceinline__ s16x8 pack_rn8(const float4 a, const float4 b) {
    union { unsigned int u[4]; s16x8 v; } P;
    const float f[8] = {a.x, a.y, a.z, a.w, b.x, b.y, b.z, b.w};
#pragma unroll
    for (int p = 0; p < 4; ++p)
        P.u[p] = (unsigned int)f2bf_rn(f[2 * p]) | ((unsigned int)f2bf_rn(f[2 * p + 1]) << 16);
    return P.v;
}

// ---- Kernel A: QKV via bf16x3 MFMA (R6 config, reverted verbatim) ----
// R10: (256,3) null -> qkv limiter is not VGPR residency. R7: VALU trim null.
// R9: fewer-blocks restructure regressed. qkv stays in its measured-best form.
__global__ __launch_bounds__(256, 2) void qkv_kernel(
    const float* __restrict__ in,
    const float* __restrict__ Wq, const float* __restrict__ bq,
    const float* __restrict__ Wk, const float* __restrict__ bk,
    const float* __restrict__ Wv, const float* __restrict__ bv,
    unsigned short* __restrict__ Qhi, unsigned short* __restrict__ Qlo,
    unsigned short* __restrict__ KhiF, unsigned short* __restrict__ VF)
{
    __shared__ float cbuf[2][4][64][20];                      // 40 KB
    __shared__ __align__(16) unsigned short stage[4096];      // 8 KB
    const int t    = threadIdx.x;
    const int w    = t >> 6;
    const int lane = t & 63;
    const int h    = lane >> 5;
    const int q32  = lane & 31;
    const int mat  = blockIdx.x >> 8;   // 0=q,1=k,2=v
    const int jt   = blockIdx.x & 255;
    const int rows0 = jt * 32;

    const float* W = (mat == 0) ? Wq : (mat == 1 ? Wk : Wv);
    const float* B = (mat == 0) ? bq : (mat == 1 ? bk : bv);

    f32x16 accA[2] = {};
    f32x16 accB[2] = {};

#pragma unroll 2
    for (int ksl = 0; ksl < 8; ++ksl) {
        const int ks = (w << 3) + ksl;
        const float* xp = in + (size_t)(rows0 + q32) * SA_IN + ks * 16 + h * 8;
        const float4 xa = *(const float4*)xp;
        const float4 xb = *(const float4*)(xp + 4);
        s16x8 xh, xl;
        split8(xa, xb, &xh, &xl);
#pragma unroll
        for (int mt = 0; mt < 2; ++mt) {
            const float* wp = W + (size_t)(mt * 32 + q32) * SA_IN + ks * 16 + h * 8;
            const float4 wa = *(const float4*)wp;
            const float4 wb = *(const float4*)(wp + 4);
            if (mat < 2) {
                s16x8 ah, al;
                split8(wa, wb, &ah, &al);
                accA[mt] = MFMA32(ah, xh, accA[mt]);
                accB[mt] = MFMA32(ah, xl, accB[mt]);
                accA[mt] = MFMA32(al, xh, accA[mt]);
            } else {
                const s16x8 ah = pack_rn8(wa, wb);
                accA[mt] = MFMA32(ah, xh, accA[mt]);
            }
        }
    }

#pragma unroll
    for (int mt = 0; mt < 2; ++mt) {
        f32x16 tot = accA[mt];
        if (mat < 2) {
#pragma unroll
            for (int r = 0; r < 16; ++r) tot[r] += accB[mt][r];
        }
#pragma unroll
        for (int rg = 0; rg < 4; ++rg) {
            float4 vv = { tot[4 * rg + 0], tot[4 * rg + 1],
                          tot[4 * rg + 2], tot[4 * rg + 3] };
            *(float4*)&cbuf[mt][w][lane][4 * rg] = vv;
        }
    }
    __syncthreads();
    if (w < 2) {
        const int mt = w;
        float c[16];
#pragma unroll
        for (int rg = 0; rg < 4; ++rg) {
            const float4 s0 = *(const float4*)&cbuf[mt][0][lane][4 * rg];
            const float4 s1 = *(const float4*)&cbuf[mt][1][lane][4 * rg];
            const float4 s2 = *(const float4*)&cbuf[mt][2][lane][4 * rg];
            const float4 s3 = *(const float4*)&cbuf[mt][3][lane][4 * rg];
            c[4 * rg + 0] = (s0.x + s1.x) + (s2.x + s3.x);
            c[4 * rg + 1] = (s0.y + s1.y) + (s2.y + s3.y);
            c[4 * rg + 2] = (s0.z + s1.z) + (s2.z + s3.z);
            c[4 * rg + 3] = (s0.w + s1.w) + (s2.w + s3.w);
        }
#pragma unroll
        for (int r = 0; r < 16; ++r) {
            const int o = mt * 32 + (r & 3) + 8 * (r >> 2) + 4 * h;
            float val = c[r] + B[o];
            if (mat == 0) {
                val *= LOG2E;
                unsigned short hi, lo;
                trunc_split(val, &hi, &lo);
                stage[q32 * 64 + o]        = hi;
                stage[2048 + q32 * 64 + o] = lo;
            } else if (mat == 1) {
                const int kl_ = ((o >> 4) * 64 + ((o >> 3) & 1) * 32 + q32) * 8 + (o & 7);
                stage[kl_] = f2bf_rn(val);
            } else {
                // pi-permuted V fragment: key q32 -> (s, h', i')
                const int hp = (q32 >> 2) & 1;
                const int ip = (q32 & 3) + ((q32 >> 3) & 1) * 4;
                const int vl_ = ((o >> 5) * 2 + (q32 >> 4)) * 512
                              + hp * 256 + (o & 31) * 8 + ip;
                stage[vl_] = f2bf_rn(val);
            }
        }
    }
    __syncthreads();

    {
        const uint4* st4 = (const uint4*)stage;
        if (mat == 0) {
            for (int i = t; i < 512; i += 256) {
                unsigned short* dst = ((i < 256) ? Qhi : Qlo) + (size_t)rows0 * 64 + (i & 255) * 8;
                *(uint4*)dst = st4[i];
            }
        } else if (mat == 1) {
            if (t < 256) *(uint4*)(KhiF + (size_t)jt * 2048 + t * 8) = st4[t];
        } else {
            *(uint4*)(VF + (size_t)jt * 2048 + t * 8) = st4[t];
        }
    }
}

// ---- Kernel B: MFMA flash attention — 8-wave LDS relay, TWO Q-tiles per wave ----
// Extends the only mechanism that ever won (R6: more MFMA per staged byte /
// per barrier): each wave owns 64 q-rows (2 tiles), so per iteration it runs
// 24 MFMA against the same 8 KB staged K/V tile; kh/vv are ds_read once and
// consumed twice. Grid 16qb x 16g = 256 blocks = 1/CU -> global K/V reads
// halve (32 MB) and LDS relay traffic per CU halves. Sequential-u structure
// (S-chain -> softmax -> PV per Q-tile) keeps peak live VGPR ~230 < 256 so
// 2 waves/SIMD stay resident under loose (512,1) bounds (R2 lesson).
__global__ __launch_bounds__(512, 1) void attn_kernel(
    const unsigned short* __restrict__ Qhi, const unsigned short* __restrict__ Qlo,
    const unsigned short* __restrict__ KhiF, const unsigned short* __restrict__ VF,
    unsigned short* __restrict__ Opart, float* __restrict__ Lpart)
{
    __shared__ __align__(16) unsigned short kbuf[2][2][2048];   // 16 KB
    const int t    = threadIdx.x;
    const int w    = t >> 6;            // 0..7
    const int lane = t & 63;
    const int h    = lane >> 5;
    const int q32  = lane & 31;
    const int qb   = blockIdx.x >> 4;   // 0..15
    const int g    = blockIdx.x & 15;
    const int q0   = qb * 512 + w * 64; // wave covers rows q0..q0+63 (2 tiles)
    const int jt0  = g * 16;

    const int half = t >> 8;            // 0 = K-stager, 1 = V-stager
    const int ti   = t & 255;

    s16x8 qh0[4], ql0[4], qh1[4], ql1[4];
#pragma unroll
    for (int s = 0; s < 4; ++s) {
        const size_t off0 = (size_t)(q0 + q32) * 64 + s * 16 + h * 8;
        const size_t off1 = (size_t)(q0 + 32 + q32) * 64 + s * 16 + h * 8;
        qh0[s] = *reinterpret_cast<const s16x8*>(Qhi + off0);
        ql0[s] = *reinterpret_cast<const s16x8*>(Qlo + off0);
        qh1[s] = *reinterpret_cast<const s16x8*>(Qhi + off1);
        ql1[s] = *reinterpret_cast<const s16x8*>(Qlo + off1);
    }

    const unsigned short* SRC = half ? VF : KhiF;

    // prologue: stage tile jt0 into buffer 0 (one uint4 per thread)
    {
        const uint4 a = *(const uint4*)(SRC + (size_t)jt0 * 2048 + ti * 8);
        *(uint4*)&kbuf[0][half][ti * 8] = a;
    }
    __syncthreads();

    f32x16 O00 = {}, O01 = {}, O10 = {}, O11 = {};
    float ls0 = 0.f, ls1 = 0.f;

    for (int it = 0; it < 16; ++it) {
        const int p = it & 1;

        // relay-prefetch next tile into registers (4 VGPR)
        uint4 na;
        if (it < 15) {
            na = *(const uint4*)(SRC + (size_t)(jt0 + it + 1) * 2048 + ti * 8);
        }

        s16x8 kh[4], vv[4];
#pragma unroll
        for (int s = 0; s < 4; ++s) {
            kh[s] = *(const s16x8*)&kbuf[p][0][(s * 64 + lane) * 8];
            vv[s] = *(const s16x8*)&kbuf[p][1][(s * 64 + lane) * 8];
        }

        // ---- Q-tile 0 ----
        {
            f32x16 Sa = {}, Sb = {};
            __builtin_amdgcn_s_setprio(1);
#pragma unroll
            for (int s = 0; s < 4; ++s) {
                Sa = MFMA32(kh[s], qh0[s], Sa);
                Sb = MFMA32(kh[s], ql0[s], Sb);
            }
            __builtin_amdgcn_s_setprio(0);

            float e[16];
#pragma unroll
            for (int r = 0; r < 16; ++r) e[r] = __builtin_amdgcn_exp2f(Sa[r] + Sb[r]);
            ls0 += (((e[0] + e[1]) + (e[2] + e[3])) + ((e[4] + e[5]) + (e[6] + e[7])))
                 + (((e[8] + e[9]) + (e[10] + e[11])) + ((e[12] + e[13]) + (e[14] + e[15])));

            union { unsigned int u[4]; s16x8 v; } P0, P1;
#pragma unroll
            for (int j2 = 0; j2 < 4; ++j2) {
                P0.u[j2] = pack_hi16(__float_as_uint(e[2 * j2]),     __float_as_uint(e[2 * j2 + 1]));
                P1.u[j2] = pack_hi16(__float_as_uint(e[8 + 2 * j2]), __float_as_uint(e[8 + 2 * j2 + 1]));
            }

            __builtin_amdgcn_s_setprio(1);
            O00 = MFMA32(vv[0], P0.v, O00);
            O00 = MFMA32(vv[1], P1.v, O00);
            O01 = MFMA32(vv[2], P0.v, O01);
            O01 = MFMA32(vv[3], P1.v, O01);
            __builtin_amdgcn_s_setprio(0);
        }

        // ---- Q-tile 1 ----
        {
            f32x16 Sa = {}, Sb = {};
            __builtin_amdgcn_s_setprio(1);
#pragma unroll
            for (int s = 0; s < 4; ++s) {
                Sa = MFMA32(kh[s], qh1[s], Sa);
                Sb = MFMA32(kh[s], ql1[s], Sb);
            }
            __builtin_amdgcn_s_setprio(0);

            float e[16];
#pragma unroll
            for (int r = 0; r < 16; ++r) e[r] = __builtin_amdgcn_exp2f(Sa[r] + Sb[r]);
            ls1 += (((e[0] + e[1]) + (e[2] + e[3])) + ((e[4] + e[5]) + (e[6] + e[7])))
                 + (((e[8] + e[9]) + (e[10] + e[11])) + ((e[12] + e[13]) + (e[14] + e[15])));

            union { unsigned int u[4]; s16x8 v; } P0, P1;
#pragma unroll
            for (int j2 = 0; j2 < 4; ++j2) {
                P0.u[j2] = pack_hi16(__float_as_uint(e[2 * j2]),     __float_as_uint(e[2 * j2 + 1]));
                P1.u[j2] = pack_hi16(__float_as_uint(e[8 + 2 * j2]), __float_as_uint(e[8 + 2 * j2 + 1]));
            }

            __builtin_amdgcn_s_setprio(1);
            O10 = MFMA32(vv[0], P0.v, O10);
            O10 = MFMA32(vv[1], P1.v, O10);
            O11 = MFMA32(vv[2], P0.v, O11);
            O11 = MFMA32(vv[3], P1.v, O11);
            __builtin_amdgcn_s_setprio(0);
        }

        if (it < 15) {
            *(uint4*)&kbuf[1 - p][half][ti * 8] = na;
        }
        __syncthreads();
    }

    ls0 += __shfl_xor(ls0, 32, 64);
    ls1 += __shfl_xor(ls1, 32, 64);

    const size_t qg0 = (size_t)g * SA_N + q0 + q32;
    const size_t qg1 = qg0 + 32;
#pragma unroll
    for (int rg = 0; rg < 4; ++rg) {
        const int d0 = 8 * rg + 4 * h;
        uint2 s0, s1;
        s0.x = (unsigned int)f2bf_rn(O00[4 * rg + 0]) | ((unsigned int)f2bf_rn(O00[4 * rg + 1]) << 16);
        s0.y = (unsigned int)f2bf_rn(O00[4 * rg + 2]) | ((unsigned int)f2bf_rn(O00[4 * rg + 3]) << 16);
        s1.x = (unsigned int)f2bf_rn(O01[4 * rg + 0]) | ((unsigned int)f2bf_rn(O01[4 * rg + 1]) << 16);
        s1.y = (unsigned int)f2bf_rn(O01[4 * rg + 2]) | ((unsigned int)f2bf_rn(O01[4 * rg + 3]) << 16);
        *(uint2*)(Opart + qg0 * 64 + d0)      = s0;
        *(uint2*)(Opart + qg0 * 64 + d0 + 32) = s1;
        uint2 t0, t1;
        t0.x = (unsigned int)f2bf_rn(O10[4 * rg + 0]) | ((unsigned int)f2bf_rn(O10[4 * rg + 1]) << 16);
        t0.y = (unsigned int)f2bf_rn(O10[4 * rg + 2]) | ((unsigned int)f2bf_rn(O10[4 * rg + 3]) << 16);
        t1.x = (unsigned int)f2bf_rn(O11[4 * rg + 0]) | ((unsigned int)f2bf_rn(O11[4 * rg + 1]) << 16);
        t1.y = (unsigned int)f2bf_rn(O11[4 * rg + 2]) | ((unsigned int)f2bf_rn(O11[4 * rg + 3]) << 16);
        *(uint2*)(Opart + qg1 * 64 + d0)      = t0;
        *(uint2*)(Opart + qg1 * 64 + d0 + 32) = t1;
    }
    if (h == 0) {
        Lpart[qg0] = ls0;
        Lpart[qg1] = ls1;
    }
}

// ---- Kernel C: combine 16 partials, normalize ----
__global__ __launch_bounds__(256) void combine_kernel(
    const unsigned short* __restrict__ Opart, const float* __restrict__ Lpart,
    float* __restrict__ out)
{
    const int tid = blockIdx.x * 256 + threadIdx.x;
    const int q  = tid >> 5;
    const int dp = tid & 31;
    const unsigned int* OP = (const unsigned int*)Opart;
    float s0 = 0.f, s1 = 0.f, lt = 0.f;
#pragma unroll
    for (int g = 0; g < G_SPL; ++g) {
        const unsigned int v = OP[((size_t)g * SA_N + q) * 32 + dp];
        s0 += __uint_as_float(v << 16);
        s1 += __uint_as_float(v & 0xFFFF0000u);
        lt += Lpart[(size_t)g * SA_N + q];
    }
    float2 r = { s0 / lt, s1 / lt };
    *(float2*)&out[(size_t)q * 64 + dp * 2] = r;
}

extern "C" void kernel_launch(void* const* d_in, const int* in_sizes, int n_in,
                              void* d_out, int out_size, void* d_ws, size_t ws_size,
                              hipStream_t stream) {
    const float* input = (const float*)d_in[0];
    const float* Wq    = (const float*)d_in[1];
    const float* bq    = (const float*)d_in[2];
    const float* Wk    = (const float*)d_in[3];
    const float* bk    = (const float*)d_in[4];
    const float* Wv    = (const float*)d_in[5];
    const float* bv    = (const float*)d_in[6];
    float* out = (float*)d_out;

    const size_t SEG = (size_t)SA_N * 64;
    unsigned short* Qhi  = (unsigned short*)d_ws;
    unsigned short* Qlo  = Qhi  + SEG;
    unsigned short* KhiF = Qlo  + SEG;
    unsigned short* VF   = KhiF + SEG;
    unsigned short* Opart = VF  + SEG;               // G_SPL*N*64 bf16 = 16 MB
    float*          Lpart = (float*)(Opart + (size_t)G_SPL * SA_N * 64);

    qkv_kernel<<<768, 256, 0, stream>>>(input, Wq, bq, Wk, bk, Wv, bv,
                                        Qhi, Qlo, KhiF, VF);
    attn_kernel<<<16 * G_SPL, 512, 0, stream>>>(Qhi, Qlo, KhiF, VF, Opart, Lpart);
    combine_kernel<<<1024, 256, 0, stream>>>(Opart, Lpart, out);
}

// Round 12
// 125.938 us; speedup vs baseline: 1.1177x; 1.0063x over previous
//
#include <hip/hip_runtime.h>
#include <math.h>

#define SA_N   8192
#define SA_IN  512
#define SA_D   64
#define G_SPL  16
#define LOG2E  1.44269504f

typedef short s16x8 __attribute__((ext_vector_type(8)));
typedef float f32x16 __attribute__((ext_vector_type(16)));

#define MFMA32(A, B, C) __builtin_amdgcn_mfma_f32_32x32x16_bf16((A), (B), (C), 0, 0, 0)

static __device__ __forceinline__ unsigned short f2bf_rn(float x) {
    unsigned int u = __float_as_uint(x);
    unsigned int r = (u + 0x7FFFu + ((u >> 16) & 1u)) >> 16;
    return (unsigned short)r;
}

static __device__ __forceinline__ void trunc_split(float f, unsigned short* hi, unsigned short* lo) {
    unsigned int u = __float_as_uint(f);
    *hi = (unsigned short)(u >> 16);
    float lf = f - __uint_as_float(u & 0xFFFF0000u);
    *lo = (unsigned short)(__float_as_uint(lf) >> 16);
}

// pack hi16 of two fp32 (trunc) into one dword — single v_perm_b32
static __device__ __forceinline__ unsigned int pack_hi16(unsigned int u0, unsigned int u1) {
    return __builtin_amdgcn_perm(u1, u0, 0x07060302u);
}

static __device__ __forceinline__ void split8(const float4 a, const float4 b, s16x8* xh, s16x8* xl) {
    union { unsigned int u[4]; s16x8 v; } H, L;
    const float f[8] = {a.x, a.y, a.z, a.w, b.x, b.y, b.z, b.w};
#pragma unroll
    for (int p = 0; p < 4; ++p) {
        const unsigned int u0 = __float_as_uint(f[2 * p]);
        const unsigned int u1 = __float_as_uint(f[2 * p + 1]);
        H.u[p] = pack_hi16(u0, u1);
        const float l0 = f[2 * p]     - __uint_as_float(u0 & 0xFFFF0000u);
        const float l1 = f[2 * p + 1] - __uint_as_float(u1 & 0xFFFF0000u);
        L.u[p] = pack_hi16(__float_as_uint(l0), __float_as_uint(l1));
    }
    *xh = H.v; *xl = L.v;
}

static __device__ __forceinline__ s16x8 pack_rn8(const float4 a, const float4 b) {
    union { unsigned int u[4]; s16x8 v; } P;
    const float f[8] = {a.x, a.y, a.z, a.w, b.x, b.y, b.z, b.w};
#pragma unroll
    for (int p = 0; p < 4; ++p)
        P.u[p] = (unsigned int)f2bf_rn(f[2 * p]) | ((unsigned int)f2bf_rn(f[2 * p + 1]) << 16);
    return P.v;
}

// ---- Kernel A: QKV via bf16x3 MFMA (R6 config — measured best; R7/R9/R10
// showed VALU trims null, restructure regresses, VGPR bound null) ----
__global__ __launch_bounds__(256, 2) void qkv_kernel(
    const float* __restrict__ in,
    const float* __restrict__ Wq, const float* __restrict__ bq,
    const float* __restrict__ Wk, const float* __restrict__ bk,
    const float* __restrict__ Wv, const float* __restrict__ bv,
    unsigned short* __restrict__ Qhi, unsigned short* __restrict__ Qlo,
    unsigned short* __restrict__ KhiF, unsigned short* __restrict__ VF)
{
    __shared__ float cbuf[2][4][64][20];                      // 40 KB
    __shared__ __align__(16) unsigned short stage[4096];      // 8 KB
    const int t    = threadIdx.x;
    const int w    = t >> 6;
    const int lane = t & 63;
    const int h    = lane >> 5;
    const int q32  = lane & 31;
    const int mat  = blockIdx.x >> 8;   // 0=q,1=k,2=v
    const int jt   = blockIdx.x & 255;
    const int rows0 = jt * 32;

    const float* W = (mat == 0) ? Wq : (mat == 1 ? Wk : Wv);
    const float* B = (mat == 0) ? bq : (mat == 1 ? bk : bv);

    f32x16 accA[2] = {};
    f32x16 accB[2] = {};

#pragma unroll 2
    for (int ksl = 0; ksl < 8; ++ksl) {
        const int ks = (w << 3) + ksl;
        const float* xp = in + (size_t)(rows0 + q32) * SA_IN + ks * 16 + h * 8;
        const float4 xa = *(const float4*)xp;
        const float4 xb = *(const float4*)(xp + 4);
        s16x8 xh, xl;
        split8(xa, xb, &xh, &xl);
#pragma unroll
        for (int mt = 0; mt < 2; ++mt) {
            const float* wp = W + (size_t)(mt * 32 + q32) * SA_IN + ks * 16 + h * 8;
            const float4 wa = *(const float4*)wp;
            const float4 wb = *(const float4*)(wp + 4);
            if (mat < 2) {
                s16x8 ah, al;
                split8(wa, wb, &ah, &al);
                accA[mt] = MFMA32(ah, xh, accA[mt]);
                accB[mt] = MFMA32(ah, xl, accB[mt]);
                accA[mt] = MFMA32(al, xh, accA[mt]);
            } else {
                const s16x8 ah = pack_rn8(wa, wb);
                accA[mt] = MFMA32(ah, xh, accA[mt]);
            }
        }
    }

#pragma unroll
    for (int mt = 0; mt < 2; ++mt) {
        f32x16 tot = accA[mt];
        if (mat < 2) {
#pragma unroll
            for (int r = 0; r < 16; ++r) tot[r] += accB[mt][r];
        }
#pragma unroll
        for (int rg = 0; rg < 4; ++rg) {
            float4 vv = { tot[4 * rg + 0], tot[4 * rg + 1],
                          tot[4 * rg + 2], tot[4 * rg + 3] };
            *(float4*)&cbuf[mt][w][lane][4 * rg] = vv;
        }
    }
    __syncthreads();
    if (w < 2) {
        const int mt = w;
        float c[16];
#pragma unroll
        for (int rg = 0; rg < 4; ++rg) {
            const float4 s0 = *(const float4*)&cbuf[mt][0][lane][4 * rg];
            const float4 s1 = *(const float4*)&cbuf[mt][1][lane][4 * rg];
            const float4 s2 = *(const float4*)&cbuf[mt][2][lane][4 * rg];
            const float4 s3 = *(const float4*)&cbuf[mt][3][lane][4 * rg];
            c[4 * rg + 0] = (s0.x + s1.x) + (s2.x + s3.x);
            c[4 * rg + 1] = (s0.y + s1.y) + (s2.y + s3.y);
            c[4 * rg + 2] = (s0.z + s1.z) + (s2.z + s3.z);
            c[4 * rg + 3] = (s0.w + s1.w) + (s2.w + s3.w);
        }
#pragma unroll
        for (int r = 0; r < 16; ++r) {
            const int o = mt * 32 + (r & 3) + 8 * (r >> 2) + 4 * h;
            float val = c[r] + B[o];
            if (mat == 0) {
                val *= LOG2E;
                unsigned short hi, lo;
                trunc_split(val, &hi, &lo);
                stage[q32 * 64 + o]        = hi;
                stage[2048 + q32 * 64 + o] = lo;
            } else if (mat == 1) {
                const int kl_ = ((o >> 4) * 64 + ((o >> 3) & 1) * 32 + q32) * 8 + (o & 7);
                stage[kl_] = f2bf_rn(val);
            } else {
                // pi-permuted V fragment: key q32 -> (s, h', i')
                const int hp = (q32 >> 2) & 1;
                const int ip = (q32 & 3) + ((q32 >> 3) & 1) * 4;
                const int vl_ = ((o >> 5) * 2 + (q32 >> 4)) * 512
                              + hp * 256 + (o & 31) * 8 + ip;
                stage[vl_] = f2bf_rn(val);
            }
        }
    }
    __syncthreads();

    {
        const uint4* st4 = (const uint4*)stage;
        if (mat == 0) {
            for (int i = t; i < 512; i += 256) {
                unsigned short* dst = ((i < 256) ? Qhi : Qlo) + (size_t)rows0 * 64 + (i & 255) * 8;
                *(uint4*)dst = st4[i];
            }
        } else if (mat == 1) {
            if (t < 256) *(uint4*)(KhiF + (size_t)jt * 2048 + t * 8) = st4[t];
        } else {
            *(uint4*)(VF + (size_t)jt * 2048 + t * 8) = st4[t];
        }
    }
}

// ---- Kernel B: MFMA flash attention — R6 8-wave LDS relay (measured best;
// R11's 2-Q-tile variant was null, reverted to the simpler proven form) ----
__global__ __launch_bounds__(512, 2) void attn_kernel(
    const unsigned short* __restrict__ Qhi, const unsigned short* __restrict__ Qlo,
    const unsigned short* __restrict__ KhiF, const unsigned short* __restrict__ VF,
    unsigned short* __restrict__ Opart, float* __restrict__ Lpart)
{
    __shared__ __align__(16) unsigned short kbuf[2][2][2048];   // 16 KB
    const int t    = threadIdx.x;
    const int w    = t >> 6;            // 0..7
    const int lane = t & 63;
    const int h    = lane >> 5;
    const int q32  = lane & 31;
    const int qb   = blockIdx.x >> 4;   // 0..31
    const int g    = blockIdx.x & 15;
    const int q0   = (qb * 8 + w) * 32;
    const int jt0  = g * 16;

    const int half = t >> 8;            // 0 = K-stager, 1 = V-stager
    const int ti   = t & 255;

    s16x8 qh[4], ql[4];
#pragma unroll
    for (int s = 0; s < 4; ++s) {
        const size_t off = (size_t)(q0 + q32) * 64 + s * 16 + h * 8;
        qh[s] = *reinterpret_cast<const s16x8*>(Qhi + off);
        ql[s] = *reinterpret_cast<const s16x8*>(Qlo + off);
    }

    const unsigned short* SRC = half ? VF : KhiF;

    // prologue: stage tile jt0 into buffer 0 (one uint4 per thread)
    {
        const uint4 a = *(const uint4*)(SRC + (size_t)jt0 * 2048 + ti * 8);
        *(uint4*)&kbuf[0][half][ti * 8] = a;
    }
    __syncthreads();

    f32x16 O0 = {}, O1 = {};
    float lsum = 0.f;

    for (int it = 0; it < 16; ++it) {
        const int p = it & 1;

        // relay-prefetch next tile into registers (4 VGPR)
        uint4 na;
        if (it < 15) {
            na = *(const uint4*)(SRC + (size_t)(jt0 + it + 1) * 2048 + ti * 8);
        }

        s16x8 kh[4], vv[4];
#pragma unroll
        for (int s = 0; s < 4; ++s) {
            kh[s] = *(const s16x8*)&kbuf[p][0][(s * 64 + lane) * 8];
            vv[s] = *(const s16x8*)&kbuf[p][1][(s * 64 + lane) * 8];
        }

        // two independent 4-deep chains
        f32x16 Sa = {}, Sb = {};
        __builtin_amdgcn_s_setprio(1);
#pragma unroll
        for (int s = 0; s < 4; ++s) {
            Sa = MFMA32(kh[s], qh[s], Sa);
            Sb = MFMA32(kh[s], ql[s], Sb);
        }
        __builtin_amdgcn_s_setprio(0);

        float e[16];
#pragma unroll
        for (int r = 0; r < 16; ++r) e[r] = __builtin_amdgcn_exp2f(Sa[r] + Sb[r]);
        lsum += (((e[0] + e[1]) + (e[2] + e[3])) + ((e[4] + e[5]) + (e[6] + e[7])))
              + (((e[8] + e[9]) + (e[10] + e[11])) + ((e[12] + e[13]) + (e[14] + e[15])));

        // P^T B-fragments = this lane's C registers in order (pi-permuted V)
        union { unsigned int u[4]; s16x8 v; } P0, P1;
#pragma unroll
        for (int j2 = 0; j2 < 4; ++j2) {
            P0.u[j2] = pack_hi16(__float_as_uint(e[2 * j2]),     __float_as_uint(e[2 * j2 + 1]));
            P1.u[j2] = pack_hi16(__float_as_uint(e[8 + 2 * j2]), __float_as_uint(e[8 + 2 * j2 + 1]));
        }

        __builtin_amdgcn_s_setprio(1);
        O0 = MFMA32(vv[0], P0.v, O0);
        O0 = MFMA32(vv[1], P1.v, O0);
        O1 = MFMA32(vv[2], P0.v, O1);
        O1 = MFMA32(vv[3], P1.v, O1);
        __builtin_amdgcn_s_setprio(0);

        if (it < 15) {
            *(uint4*)&kbuf[1 - p][half][ti * 8] = na;
        }
        __syncthreads();
    }

    lsum += __shfl_xor(lsum, 32, 64);

    const size_t qg = (size_t)g * SA_N + q0 + q32;
#pragma unroll
    for (int rg = 0; rg < 4; ++rg) {
        const int d0 = 8 * rg + 4 * h;
        uint2 s0, s1;
        s0.x = (unsigned int)f2bf_rn(O0[4 * rg + 0]) | ((unsigned int)f2bf_rn(O0[4 * rg + 1]) << 16);
        s0.y = (unsigned int)f2bf_rn(O0[4 * rg + 2]) | ((unsigned int)f2bf_rn(O0[4 * rg + 3]) << 16);
        s1.x = (unsigned int)f2bf_rn(O1[4 * rg + 0]) | ((unsigned int)f2bf_rn(O1[4 * rg + 1]) << 16);
        s1.y = (unsigned int)f2bf_rn(O1[4 * rg + 2]) | ((unsigned int)f2bf_rn(O1[4 * rg + 3]) << 16);
        *(uint2*)(Opart + qg * 64 + d0)      = s0;
        *(uint2*)(Opart + qg * 64 + d0 + 32) = s1;
    }
    if (h == 0) Lpart[qg] = lsum;
}

// ---- Kernel C: combine 16 partials, normalize ----
// R12 change: (a) Lpart was redundantly loaded by all 32 lanes of each q-row
// (16.8 MB of 32x-amplified reads + a 16-deep serial L2 latency chain);
// now each lane reads at most one distinct Lpart value (lanes dp<16) and a
// 5-step shfl_xor tree broadcasts the total. (b) O-accumulation split into
// two independent 8-deep chains for memory-level parallelism.
__global__ __launch_bounds__(256) void combine_kernel(
    const unsigned short* __restrict__ Opart, const float* __restrict__ Lpart,
    float* __restrict__ out)
{
    const int tid = blockIdx.x * 256 + threadIdx.x;
    const int q  = tid >> 5;
    const int dp = tid & 31;
    const unsigned int* OP = (const unsigned int*)Opart;

    // lane-split L reduction: lane dp reads Lpart[dp] for dp<16, else 0
    float lt = (dp < G_SPL) ? Lpart[(size_t)dp * SA_N + q] : 0.f;
    lt += __shfl_xor(lt, 1,  32);
    lt += __shfl_xor(lt, 2,  32);
    lt += __shfl_xor(lt, 4,  32);
    lt += __shfl_xor(lt, 8,  32);
    lt += __shfl_xor(lt, 16, 32);      // all 32 lanes now hold the total

    float a0 = 0.f, a1 = 0.f, b0 = 0.f, b1 = 0.f;
#pragma unroll
    for (int g = 0; g < G_SPL / 2; ++g) {
        const unsigned int va = OP[((size_t)g * SA_N + q) * 32 + dp];
        const unsigned int vb = OP[((size_t)(g + G_SPL / 2) * SA_N + q) * 32 + dp];
        a0 += __uint_as_float(va << 16);
        a1 += __uint_as_float(va & 0xFFFF0000u);
        b0 += __uint_as_float(vb << 16);
        b1 += __uint_as_float(vb & 0xFFFF0000u);
    }
    float2 r = { (a0 + b0) / lt, (a1 + b1) / lt };
    *(float2*)&out[(size_t)q * 64 + dp * 2] = r;
}

extern "C" void kernel_launch(void* const* d_in, const int* in_sizes, int n_in,
                              void* d_out, int out_size, void* d_ws, size_t ws_size,
                              hipStream_t stream) {
    const float* input = (const float*)d_in[0];
    const float* Wq    = (const float*)d_in[1];
    const float* bq    = (const float*)d_in[2];
    const float* Wk    = (const float*)d_in[3];
    const float* bk    = (const float*)d_in[4];
    const float* Wv    = (const float*)d_in[5];
    const float* bv    = (const float*)d_in[6];
    float* out = (float*)d_out;

    const size_t SEG = (size_t)SA_N * 64;
    unsigned short* Qhi  = (unsigned short*)d_ws;
    unsigned short* Qlo  = Qhi  + SEG;
    unsigned short* KhiF = Qlo  + SEG;
    unsigned short* VF   = KhiF + SEG;
    unsigned short* Opart = VF  + SEG;               // G_SPL*N*64 bf16 = 16 MB
    float*          Lpart = (float*)(Opart + (size_t)G_SPL * SA_N * 64);

    qkv_kernel<<<768, 256, 0, stream>>>(input, Wq, bq, Wk, bk, Wv, bv,
                                        Qhi, Qlo, KhiF, VF);
    attn_kernel<<<32 * G_SPL, 512, 0, stream>>>(Qhi, Qlo, KhiF, VF, Opart, Lpart);
    combine_kernel<<<1024, 256, 0, stream>>>(Opart, Lpart, out);
}